// Round 8
// baseline (1021.288 us; speedup 1.0000x reference)
//
#include <hip/hip_runtime.h>
#include <hip/hip_bf16.h>

#define NN 100000   // nodes
#define FF 10       // input features
#define HH 20       // hidden dim
#define GG 512      // graphs
#define LL 2        // labels

#define NB 500      // dst buckets
#define BNODES 200  // nodes per bucket (NN / NB)
#define CAP 7168    // per-bucket capacity (mean 6400, sigma ~80 -> 9.6 sigma)
#define TILE 4096   // edges per block in multisplit
#define SRC_BITS 17
#define SRC_MASK 0x1FFFFu

// bf16 helpers (storage-only; all math in f32)
__device__ inline unsigned short f2bf(float f) {
  unsigned u = __float_as_uint(f);
  unsigned r = u + 0x7FFFu + ((u >> 16) & 1u);
  return (unsigned short)(r >> 16);
}
__device__ inline float bflo(unsigned u) { return __uint_as_float(u << 16); }
__device__ inline float bfhi(unsigned u) { return __uint_as_float(u & 0xFFFF0000u); }

// ---------------------------------------------------------------------------
// Cast x f32->bf16 and zero accumulators / cursors (folded memsets).
// ---------------------------------------------------------------------------
__global__ __launch_bounds__(256) void cast_init_kernel(
    const float* __restrict__ x, unsigned short* __restrict__ xb,
    float* __restrict__ sump, int* __restrict__ maxp, float* __restrict__ cnt,
    int* __restrict__ cursor, int n) {
  int i = blockIdx.x * 256 + threadIdx.x;
  if (i < n) xb[i] = f2bf(x[i]);
  if (i < GG * HH) {
    sump[i] = 0.0f;
    maxp[i] = 0;
  }
  if (i < GG) cnt[i] = 0.0f;
  if (i < NB) cursor[i] = 0;
}

// ---------------------------------------------------------------------------
// Multisplit with LDS-staged COALESCED writes into fixed-CAP bucket regions.
// Pass 1: LDS histogram (plain dst load, keeps tile L2-hot).
// Reserve: one global atomic per (block, non-empty bucket); scan lhist->lofs.
// Pass 2: re-read tile, rank via lcur, scatter payload into sord (grouped by
// bucket), then write runs contiguously (full-line traffic).
// Payload pack: (local_dst << 17) | src.
// ---------------------------------------------------------------------------
__global__ __launch_bounds__(256) void multisplit_kernel(
    const int* __restrict__ src, const int* __restrict__ dst,
    int* __restrict__ cursor, unsigned int* __restrict__ pay, int E) {
  __shared__ int lhist[NB];
  __shared__ int lofs[NB];
  __shared__ int gbase[NB];
  __shared__ int lcur[NB];
  __shared__ unsigned int sord[TILE];
  __shared__ unsigned short sdbk[TILE];
  __shared__ int ss[512];
  int t = threadIdx.x;
  for (int i = t; i < NB; i += 256) lhist[i] = 0;
  __syncthreads();

  int base = blockIdx.x * TILE;
  int count = E - base;
  if (count > TILE) count = TILE;

  for (int i = t; i < count; i += 256)
    atomicAdd(&lhist[dst[base + i] / BNODES], 1);
  __syncthreads();

  // exclusive scan of lhist (NB=500) with 256 threads x 2 elements
  int own0 = (t < NB) ? lhist[t] : 0;
  int own1 = (t + 256 < NB) ? lhist[t + 256] : 0;
  ss[t] = own0;
  ss[t + 256] = own1;
  __syncthreads();
  for (int off = 1; off < 512; off <<= 1) {
    int a0 = (t >= off) ? ss[t - off] : 0;
    int a1 = (t + 256 >= off) ? ss[t + 256 - off] : 0;
    __syncthreads();
    ss[t] += a0;
    ss[t + 256] += a1;
    __syncthreads();
  }
  // reserve global ranges (clamped defensively: a >9-sigma overflow drops
  // edges instead of corrupting neighboring regions)
  if (t < NB) {
    lofs[t] = ss[t] - own0;
    int base_off = own0 ? atomicAdd(&cursor[t], own0) : 0;
    if (base_off > CAP - own0) base_off = CAP - own0;  // never OOB
    gbase[t] = t * CAP + base_off;
    lcur[t] = 0;
  }
  if (t + 256 < NB) {
    lofs[t + 256] = ss[t + 256] - own1;
    int base_off = own1 ? atomicAdd(&cursor[t + 256], own1) : 0;
    if (base_off > CAP - own1) base_off = CAP - own1;
    gbase[t + 256] = (t + 256) * CAP + base_off;
    lcur[t + 256] = 0;
  }
  __syncthreads();

  // pass 2: rank + scatter into bucket-grouped LDS order
  for (int i = t; i < count; i += 256) {
    int e = base + i;
    int d = __builtin_nontemporal_load(dst + e);
    int s = __builtin_nontemporal_load(src + e);
    int bk = d / BNODES;
    int ld = d - bk * BNODES;
    int r = atomicAdd(&lcur[bk], 1);
    int slot = lofs[bk] + r;
    sord[slot] = ((unsigned)ld << SRC_BITS) | (unsigned)s;
    sdbk[slot] = (unsigned short)bk;
  }
  __syncthreads();

  // coalesced run writes
  for (int i = t; i < count; i += 256) {
    int bk = sdbk[i];
    pay[gbase[bk] + (i - lofs[bk])] = sord[i];
  }
}

// ---------------------------------------------------------------------------
// Fused bucket layer: one 512-thread block owns a 200-node bucket.
// 1) stage weights + root rows (coalesced), zero padded LDS acc
// 2) stream bucket payload run; gather source rows; accumulate via
//    ds_add_f32 LDS atomics (stride padded coprime-32 -> ~2-way conflicts)
// 3) dense + bias + root + ReLU from LDS; write bf16 h_out
// ---------------------------------------------------------------------------
template<int DIN>
__global__ __launch_bounds__(512) void bucket_layer_kernel(
    const unsigned int* __restrict__ pay, const int* __restrict__ cursor,
    const unsigned short* __restrict__ hin, const float* __restrict__ Wrel,
    const float* __restrict__ bias, const float* __restrict__ Wroot,
    unsigned short* __restrict__ hout) {
  constexpr int AST = (DIN == 10) ? 11 : 21;  // padded acc stride
  __shared__ float acc[BNODES * AST];
  __shared__ unsigned short roots[BNODES * DIN];
  __shared__ float sWrel[DIN * HH];
  __shared__ float sWroot[DIN * HH];
  __shared__ float sb[HH];
  int b = blockIdx.x;
  int t = threadIdx.x;
  int nbase = b * BNODES;

  for (int i = t; i < DIN * HH; i += 512) {
    sWrel[i] = Wrel[i];
    sWroot[i] = Wroot[i];
  }
  if (t < HH) sb[t] = bias[t];
  for (int i = t; i < BNODES * AST; i += 512) acc[i] = 0.0f;
  {  // stage root rows coalesced (uint granularity; counts are even)
    const unsigned* rs = (const unsigned*)(hin + (size_t)nbase * DIN);
    unsigned* rd = (unsigned*)roots;
    for (int i = t; i < BNODES * DIN / 2; i += 512) rd[i] = rs[i];
  }
  __syncthreads();

  int ecnt = cursor[b];
  if (ecnt > CAP) ecnt = CAP;
  const unsigned int* mypay = pay + (size_t)b * CAP;
  for (int i = t; i < ecnt; i += 512) {
    unsigned p = mypay[i];
    int ld = p >> SRC_BITS;
    int s = (int)(p & SRC_MASK);
    float* a = acc + ld * AST;
    if (DIN == 20) {
      const uint2* xp = (const uint2*)(hin + (size_t)s * 20);
      uint2 u0 = xp[0], u1 = xp[1], u2 = xp[2], u3 = xp[3], u4 = xp[4];
      atomicAdd(a + 0, bflo(u0.x));  atomicAdd(a + 1, bfhi(u0.x));
      atomicAdd(a + 2, bflo(u0.y));  atomicAdd(a + 3, bfhi(u0.y));
      atomicAdd(a + 4, bflo(u1.x));  atomicAdd(a + 5, bfhi(u1.x));
      atomicAdd(a + 6, bflo(u1.y));  atomicAdd(a + 7, bfhi(u1.y));
      atomicAdd(a + 8, bflo(u2.x));  atomicAdd(a + 9, bfhi(u2.x));
      atomicAdd(a + 10, bflo(u2.y)); atomicAdd(a + 11, bfhi(u2.y));
      atomicAdd(a + 12, bflo(u3.x)); atomicAdd(a + 13, bfhi(u3.x));
      atomicAdd(a + 14, bflo(u3.y)); atomicAdd(a + 15, bfhi(u3.y));
      atomicAdd(a + 16, bflo(u4.x)); atomicAdd(a + 17, bfhi(u4.x));
      atomicAdd(a + 18, bflo(u4.y)); atomicAdd(a + 19, bfhi(u4.y));
    } else {
      const unsigned* xp = (const unsigned*)(hin + (size_t)s * 10);
      unsigned u0 = xp[0], u1 = xp[1], u2 = xp[2], u3 = xp[3], u4 = xp[4];
      atomicAdd(a + 0, bflo(u0)); atomicAdd(a + 1, bfhi(u0));
      atomicAdd(a + 2, bflo(u1)); atomicAdd(a + 3, bfhi(u1));
      atomicAdd(a + 4, bflo(u2)); atomicAdd(a + 5, bfhi(u2));
      atomicAdd(a + 6, bflo(u3)); atomicAdd(a + 7, bfhi(u3));
      atomicAdd(a + 8, bflo(u4)); atomicAdd(a + 9, bfhi(u4));
    }
  }
  __syncthreads();

  for (int idx = t; idx < BNODES * HH; idx += 512) {
    int ln = idx / HH;
    int j = idx - ln * HH;
    const float* a = acc + ln * AST;
    const unsigned short* r = roots + ln * DIN;
    float v = sb[j];
#pragma unroll
    for (int f = 0; f < DIN; f++) {
      v += a[f] * sWrel[f * HH + j];
      v += bflo((unsigned)r[f]) * sWroot[f * HH + j];
    }
    hout[(size_t)nbase * HH + idx] = f2bf(fmaxf(v, 0.0f));
  }
}

// ---------------------------------------------------------------------------
// Layer 3 + pooling: same as above but keeps dense output in LDS and pools
// block-locally (bucket spans few sorted graphs), then few global atomics.
// Post-ReLU >= 0 -> int atomicMax on float bits order-correct; zero init
// reproduces where(cnt>0, max, 0).
// ---------------------------------------------------------------------------
__global__ __launch_bounds__(512) void bucket_layer_pool_kernel(
    const unsigned int* __restrict__ pay, const int* __restrict__ cursor,
    const unsigned short* __restrict__ hin, const float* __restrict__ Wrel,
    const float* __restrict__ bias, const float* __restrict__ Wroot,
    const int* __restrict__ batch, float* __restrict__ sump,
    int* __restrict__ maxp, float* __restrict__ cnt) {
  constexpr int DIN = 20;
  constexpr int AST = 21;
  __shared__ float acc[BNODES * AST];
  __shared__ unsigned short roots[BNODES * DIN];
  __shared__ float sOut[BNODES * HH];
  __shared__ int sBatch[BNODES];
  __shared__ float sWrel[DIN * HH];
  __shared__ float sWroot[DIN * HH];
  __shared__ float sb[HH];
  int b = blockIdx.x;
  int t = threadIdx.x;
  int nbase = b * BNODES;

  for (int i = t; i < DIN * HH; i += 512) {
    sWrel[i] = Wrel[i];
    sWroot[i] = Wroot[i];
  }
  if (t < HH) sb[t] = bias[t];
  for (int i = t; i < BNODES * AST; i += 512) acc[i] = 0.0f;
  if (t < BNODES) sBatch[t] = batch[nbase + t];
  {
    const unsigned* rs = (const unsigned*)(hin + (size_t)nbase * DIN);
    unsigned* rd = (unsigned*)roots;
    for (int i = t; i < BNODES * DIN / 2; i += 512) rd[i] = rs[i];
  }
  __syncthreads();

  int ecnt = cursor[b];
  if (ecnt > CAP) ecnt = CAP;
  const unsigned int* mypay = pay + (size_t)b * CAP;
  for (int i = t; i < ecnt; i += 512) {
    unsigned p = mypay[i];
    int ld = p >> SRC_BITS;
    int s = (int)(p & SRC_MASK);
    float* a = acc + ld * AST;
    const uint2* xp = (const uint2*)(hin + (size_t)s * 20);
    uint2 u0 = xp[0], u1 = xp[1], u2 = xp[2], u3 = xp[3], u4 = xp[4];
    atomicAdd(a + 0, bflo(u0.x));  atomicAdd(a + 1, bfhi(u0.x));
    atomicAdd(a + 2, bflo(u0.y));  atomicAdd(a + 3, bfhi(u0.y));
    atomicAdd(a + 4, bflo(u1.x));  atomicAdd(a + 5, bfhi(u1.x));
    atomicAdd(a + 6, bflo(u1.y));  atomicAdd(a + 7, bfhi(u1.y));
    atomicAdd(a + 8, bflo(u2.x));  atomicAdd(a + 9, bfhi(u2.x));
    atomicAdd(a + 10, bflo(u2.y)); atomicAdd(a + 11, bfhi(u2.y));
    atomicAdd(a + 12, bflo(u3.x)); atomicAdd(a + 13, bfhi(u3.x));
    atomicAdd(a + 14, bflo(u3.y)); atomicAdd(a + 15, bfhi(u3.y));
    atomicAdd(a + 16, bflo(u4.x)); atomicAdd(a + 17, bfhi(u4.x));
    atomicAdd(a + 18, bflo(u4.y)); atomicAdd(a + 19, bfhi(u4.y));
  }
  __syncthreads();

  for (int idx = t; idx < BNODES * HH; idx += 512) {
    int ln = idx / HH;
    int j = idx - ln * HH;
    const float* a = acc + ln * AST;
    const unsigned short* r = roots + ln * DIN;
    float v = sb[j];
#pragma unroll
    for (int f = 0; f < DIN; f++) {
      v += a[f] * sWrel[f * HH + j];
      v += bflo((unsigned)r[f]) * sWroot[f * HH + j];
    }
    sOut[idx] = fmaxf(v, 0.0f);
  }
  __syncthreads();

  // block-local pool over the graphs this bucket spans
  int g0 = sBatch[0];
  int g1 = sBatch[BNODES - 1];
  int ngr = g1 - g0 + 1;
  for (int it = t; it < ngr * HH; it += 512) {
    int gi = it / HH;
    int j = it - gi * HH;
    int g = g0 + gi;
    float s = 0.0f, m = 0.0f;
    int c = 0;
    for (int ln = 0; ln < BNODES; ln++) {
      if (sBatch[ln] == g) {
        float v = sOut[ln * HH + j];
        s += v;
        m = fmaxf(m, v);
        c++;
      }
    }
    if (c) {
      atomicAdd(&sump[g * HH + j], s);
      atomicMax(&maxp[g * HH + j], __float_as_int(m));
      if (j == 0) atomicAdd(&cnt[g], (float)c);
    }
  }
}

__global__ __launch_bounds__(256) void readout_kernel(
    const float* __restrict__ sump, const int* __restrict__ maxp,
    const float* __restrict__ cnt, const float* __restrict__ Wlin,
    const float* __restrict__ blin, float* __restrict__ out) {
  int idx = blockIdx.x * 256 + threadIdx.x;
  if (idx >= GG * LL) return;
  int g = idx / LL;
  int l = idx - g * LL;
  float c = cnt[g];
  float inv = 1.0f / fmaxf(c, 1.0f);
  float acc = blin[l];
#pragma unroll
  for (int j = 0; j < HH; j++) {
    float mx = __int_as_float(maxp[g * HH + j]);
    float mean = sump[g * HH + j] * inv;
    acc += mx * Wlin[j * LL + l];
    acc += mean * Wlin[(HH + j) * LL + l];
  }
  out[idx] = acc;
}

extern "C" void kernel_launch(void* const* d_in, const int* in_sizes, int n_in,
                              void* d_out, int out_size, void* d_ws,
                              size_t ws_size, hipStream_t stream) {
  const float* x = (const float*)d_in[0];
  const int* edge_index = (const int*)d_in[1];
  const int* batch = (const int*)d_in[2];
  const float* W_rel1 = (const float*)d_in[3];
  const float* b1 = (const float*)d_in[4];
  const float* W_root1 = (const float*)d_in[5];
  const float* W_rel2 = (const float*)d_in[6];
  const float* b2 = (const float*)d_in[7];
  const float* W_root2 = (const float*)d_in[8];
  const float* W_rel3 = (const float*)d_in[9];
  const float* b3 = (const float*)d_in[10];
  const float* W_root3 = (const float*)d_in[11];
  const float* W_lin = (const float*)d_in[12];
  const float* b_lin = (const float*)d_in[13];
  float* out = (float*)d_out;

  const int E = in_sizes[1] / 2;
  const int n_nodes = in_sizes[0] / FF;  // == NN
  const int* src = edge_index;
  const int* dst = edge_index + E;

  // Workspace layout (chunks 16B aligned)
  unsigned int* pay = (unsigned int*)d_ws;       // NB*CAP u32 (14.3MB)
  int* cursor = (int*)(pay + (size_t)NB * CAP);  // 512
  float* sump = (float*)(cursor + 512);          // GG*HH
  int* maxp = (int*)(sump + GG * HH);            // GG*HH
  float* cnt = (float*)(maxp + GG * HH);         // 512
  unsigned short* xb = (unsigned short*)(cnt + 512);  // NN*FF bf16 (2MB)
  unsigned short* h1 = xb + (size_t)NN * FF;     // NN*HH bf16 (4MB)
  unsigned short* h2 = h1 + (size_t)NN * HH;     // NN*HH bf16 (4MB)

  const int edge_tiles = (E + TILE - 1) / TILE;

  // ---- Cast x to bf16 + zero accumulators/cursors ----
  cast_init_kernel<<<(n_nodes * FF + 255) / 256, 256, 0, stream>>>(
      x, xb, sump, maxp, cnt, cursor, n_nodes * FF);

  // ---- Edge partition: staged multisplit into fixed bucket regions ----
  multisplit_kernel<<<edge_tiles, 256, 0, stream>>>(src, dst, cursor, pay, E);

  // ---- Fused per-bucket layers ----
  bucket_layer_kernel<FF><<<NB, 512, 0, stream>>>(
      pay, cursor, xb, W_rel1, b1, W_root1, h1);
  bucket_layer_kernel<HH><<<NB, 512, 0, stream>>>(
      pay, cursor, h1, W_rel2, b2, W_root2, h2);
  bucket_layer_pool_kernel<<<NB, 512, 0, stream>>>(
      pay, cursor, h2, W_rel3, b3, W_root3, batch, sump, maxp, cnt);

  // ---- Readout ----
  readout_kernel<<<(GG * LL + 255) / 256, 256, 0, stream>>>(
      sump, maxp, cnt, W_lin, b_lin, out);
}

// Round 9
// 270.844 us; speedup vs baseline: 3.7708x; 3.7708x over previous
//
#include <hip/hip_runtime.h>
#include <hip/hip_bf16.h>

#define NN 100000   // nodes
#define FF 10       // input features
#define HH 20       // hidden dim
#define GG 512      // graphs
#define LL 2        // labels

#define NB 500      // dst buckets
#define BNODES 200  // nodes per bucket (NN / NB)
#define CAP 7168    // per-bucket capacity (mean 6400, sigma ~80 -> 9.6 sigma)
#define STASH 14    // CAP / 512
#define TILE 4096   // edges per block in multisplit
#define SRC_BITS 17
#define SRC_MASK 0x1FFFFu

// bf16 helpers (storage-only; all math in f32)
__device__ inline unsigned short f2bf(float f) {
  unsigned u = __float_as_uint(f);
  unsigned r = u + 0x7FFFu + ((u >> 16) & 1u);
  return (unsigned short)(r >> 16);
}
__device__ inline float bflo(unsigned u) { return __uint_as_float(u << 16); }
__device__ inline float bfhi(unsigned u) { return __uint_as_float(u & 0xFFFF0000u); }

// ---------------------------------------------------------------------------
// Cast x f32->bf16 and zero accumulators / cursors (folded memsets).
// ---------------------------------------------------------------------------
__global__ __launch_bounds__(256) void cast_init_kernel(
    const float* __restrict__ x, unsigned short* __restrict__ xb,
    float* __restrict__ sump, int* __restrict__ maxp, float* __restrict__ cnt,
    int* __restrict__ cursor, int n) {
  int i = blockIdx.x * 256 + threadIdx.x;
  if (i < n) xb[i] = f2bf(x[i]);
  if (i < GG * HH) {
    sump[i] = 0.0f;
    maxp[i] = 0;
  }
  if (i < GG) cnt[i] = 0.0f;
  if (i < NB) cursor[i] = 0;
}

// ---------------------------------------------------------------------------
// Multisplit with LDS-staged COALESCED writes into fixed-CAP bucket regions.
// Payload pack: (local_dst << 17) | src.
// ---------------------------------------------------------------------------
__global__ __launch_bounds__(256) void multisplit_kernel(
    const int* __restrict__ src, const int* __restrict__ dst,
    int* __restrict__ cursor, unsigned int* __restrict__ pay, int E) {
  __shared__ int lhist[NB];
  __shared__ int lofs[NB];
  __shared__ int gbase[NB];
  __shared__ int lcur[NB];
  __shared__ unsigned int sord[TILE];
  __shared__ unsigned short sdbk[TILE];
  __shared__ int ss[512];
  int t = threadIdx.x;
  for (int i = t; i < NB; i += 256) lhist[i] = 0;
  __syncthreads();

  int base = blockIdx.x * TILE;
  int count = E - base;
  if (count > TILE) count = TILE;

  for (int i = t; i < count; i += 256)
    atomicAdd(&lhist[dst[base + i] / BNODES], 1);
  __syncthreads();

  // exclusive scan of lhist (NB=500) with 256 threads x 2 elements
  int own0 = (t < NB) ? lhist[t] : 0;
  int own1 = (t + 256 < NB) ? lhist[t + 256] : 0;
  ss[t] = own0;
  ss[t + 256] = own1;
  __syncthreads();
  for (int off = 1; off < 512; off <<= 1) {
    int a0 = (t >= off) ? ss[t - off] : 0;
    int a1 = (t + 256 >= off) ? ss[t + 256 - off] : 0;
    __syncthreads();
    ss[t] += a0;
    ss[t + 256] += a1;
    __syncthreads();
  }
  // reserve global ranges (clamped: >9-sigma overflow drops edges, no OOB)
  if (t < NB) {
    lofs[t] = ss[t] - own0;
    int bo = own0 ? atomicAdd(&cursor[t], own0) : 0;
    if (bo > CAP - own0) bo = CAP - own0;
    gbase[t] = t * CAP + bo;
    lcur[t] = 0;
  }
  if (t + 256 < NB) {
    lofs[t + 256] = ss[t + 256] - own1;
    int bo = own1 ? atomicAdd(&cursor[t + 256], own1) : 0;
    if (bo > CAP - own1) bo = CAP - own1;
    gbase[t + 256] = (t + 256) * CAP + bo;
    lcur[t + 256] = 0;
  }
  __syncthreads();

  // pass 2: rank + scatter into bucket-grouped LDS order
  for (int i = t; i < count; i += 256) {
    int e = base + i;
    int d = __builtin_nontemporal_load(dst + e);
    int s = __builtin_nontemporal_load(src + e);
    int bk = d / BNODES;
    int ld = d - bk * BNODES;
    int r = atomicAdd(&lcur[bk], 1);
    int slot = lofs[bk] + r;
    sord[slot] = ((unsigned)ld << SRC_BITS) | (unsigned)s;
    sdbk[slot] = (unsigned short)bk;
  }
  __syncthreads();

  // coalesced run writes
  for (int i = t; i < count; i += 256) {
    int bk = sdbk[i];
    pay[gbase[bk] + (i - lofs[bk])] = sord[i];
  }
}

// ---------------------------------------------------------------------------
// Fused bucket layer, register-accumulated:
//  A) stash pay run in registers; build block-local CSR in LDS
//     (1 LDS atomic/edge for hist + 1 scatter write — NOT 20 atomics/edge)
//  B) gather: task = (local node, chunk); 5 consecutive threads share a node
//     (LDS index reads broadcast); 8B/4B global row loads; VGPR accumulate;
//     one plain LDS store per task into padded acc
//  C) dense + bias + root + ReLU from LDS -> bf16 hout
// ---------------------------------------------------------------------------
template<int DIN>
__global__ __launch_bounds__(512) void bucket_layer_kernel(
    const unsigned int* __restrict__ pay, const int* __restrict__ cursor,
    const unsigned short* __restrict__ hin, const float* __restrict__ Wrel,
    const float* __restrict__ bias, const float* __restrict__ Wroot,
    unsigned short* __restrict__ hout) {
  constexpr int AST = (DIN == 10) ? 11 : 21;  // padded acc stride
  constexpr int CH = DIN / 5;                 // features per chunk (2 or 4)
  __shared__ int sSrc[CAP];
  __shared__ float acc[BNODES * AST];
  __shared__ unsigned short roots[BNODES * DIN];
  __shared__ float sWrel[DIN * HH];
  __shared__ float sWroot[DIN * HH];
  __shared__ float sb[HH];
  __shared__ int lhist[BNODES];
  __shared__ int lcur[BNODES];
  __shared__ int sRofs[BNODES];
  __shared__ int sRend[BNODES];
  __shared__ int ss[256];
  int b = blockIdx.x;
  int t = threadIdx.x;
  int nbase = b * BNODES;

  for (int i = t; i < DIN * HH; i += 512) {
    sWrel[i] = Wrel[i];
    sWroot[i] = Wroot[i];
  }
  if (t < HH) sb[t] = bias[t];
  if (t < BNODES) lhist[t] = 0;
  {  // stage root rows coalesced
    const unsigned* rs = (const unsigned*)(hin + (size_t)nbase * DIN);
    unsigned* rd = (unsigned*)roots;
    for (int i = t; i < BNODES * DIN / 2; i += 512) rd[i] = rs[i];
  }
  __syncthreads();

  int ecnt = cursor[b];
  if (ecnt > CAP) ecnt = CAP;
  const unsigned int* mypay = pay + (size_t)b * CAP;

  // A1: stash + histogram
  unsigned ps[STASH];
#pragma unroll
  for (int u = 0; u < STASH; u++) {
    int i = t + u * 512;
    if (i < ecnt) {
      unsigned p = mypay[i];
      ps[u] = p;
      atomicAdd(&lhist[p >> SRC_BITS], 1);
    }
  }
  __syncthreads();

  // A2: scan (200 entries, first 256 threads)
  int own = (t < BNODES) ? lhist[t] : 0;
  if (t < 256) ss[t] = own;
  __syncthreads();
  for (int off = 1; off < 256; off <<= 1) {
    int a0 = (t < 256 && t >= off) ? ss[t - off] : 0;
    __syncthreads();
    if (t < 256) ss[t] += a0;
    __syncthreads();
  }
  if (t < BNODES) {
    int ex = ss[t] - own;
    sRofs[t] = ex;
    sRend[t] = ex + own;
    lcur[t] = 0;
  }
  __syncthreads();

  // A3: scatter src into node-sorted LDS order
#pragma unroll
  for (int u = 0; u < STASH; u++) {
    int i = t + u * 512;
    if (i < ecnt) {
      unsigned p = ps[u];
      int ld = p >> SRC_BITS;
      int r = atomicAdd(&lcur[ld], 1);
      sSrc[sRofs[ld] + r] = (int)(p & SRC_MASK);
    }
  }
  __syncthreads();

  // B: gather with register accumulation
  for (int task = t; task < BNODES * 5; task += 512) {
    int ln = task / 5;
    int c = task - ln * 5;
    int k0 = sRofs[ln], k1 = sRend[ln];
    if (CH == 4) {
      float a0 = 0, a1 = 0, a2 = 0, a3 = 0;
      const unsigned short* xb = hin + c * 4;
      for (int k = k0; k < k1; k++) {
        int s = sSrc[k];
        uint2 u = *(const uint2*)(xb + (size_t)s * 20);
        a0 += bflo(u.x);
        a1 += bfhi(u.x);
        a2 += bflo(u.y);
        a3 += bfhi(u.y);
      }
      float* a = acc + ln * AST + c * 4;
      a[0] = a0; a[1] = a1; a[2] = a2; a[3] = a3;
    } else {
      float a0 = 0, a1 = 0;
      const unsigned short* xb = hin + c * 2;
      for (int k = k0; k < k1; k++) {
        int s = sSrc[k];
        unsigned u = *(const unsigned*)(xb + (size_t)s * 10);
        a0 += bflo(u);
        a1 += bfhi(u);
      }
      float* a = acc + ln * AST + c * 2;
      a[0] = a0; a[1] = a1;
    }
  }
  __syncthreads();

  // C: dense + bias + root + relu -> global bf16
  for (int idx = t; idx < BNODES * HH; idx += 512) {
    int ln = idx / HH;
    int j = idx - ln * HH;
    const float* a = acc + ln * AST;
    const unsigned short* r = roots + ln * DIN;
    float v = sb[j];
#pragma unroll
    for (int f = 0; f < DIN; f++) {
      v += a[f] * sWrel[f * HH + j];
      v += bflo((unsigned)r[f]) * sWroot[f * HH + j];
    }
    hout[(size_t)nbase * HH + idx] = f2bf(fmaxf(v, 0.0f));
  }
}

// ---------------------------------------------------------------------------
// Layer 3 + pooling: same as above; dense results staged in registers then
// written back over acc (it is dead), then block-local pool + few global
// atomics. Post-ReLU >= 0 -> int atomicMax on float bits order-correct;
// zero init reproduces where(cnt>0, max, 0).
// ---------------------------------------------------------------------------
__global__ __launch_bounds__(512) void bucket_layer_pool_kernel(
    const unsigned int* __restrict__ pay, const int* __restrict__ cursor,
    const unsigned short* __restrict__ hin, const float* __restrict__ Wrel,
    const float* __restrict__ bias, const float* __restrict__ Wroot,
    const int* __restrict__ batch, float* __restrict__ sump,
    int* __restrict__ maxp, float* __restrict__ cnt) {
  constexpr int DIN = 20;
  constexpr int AST = 21;
  __shared__ int sSrc[CAP];
  __shared__ float acc[BNODES * AST];
  __shared__ unsigned short roots[BNODES * DIN];
  __shared__ int sBatch[BNODES];
  __shared__ float sWrel[DIN * HH];
  __shared__ float sWroot[DIN * HH];
  __shared__ float sb[HH];
  __shared__ int lhist[BNODES];
  __shared__ int lcur[BNODES];
  __shared__ int sRofs[BNODES];
  __shared__ int sRend[BNODES];
  __shared__ int ss[256];
  int b = blockIdx.x;
  int t = threadIdx.x;
  int nbase = b * BNODES;

  for (int i = t; i < DIN * HH; i += 512) {
    sWrel[i] = Wrel[i];
    sWroot[i] = Wroot[i];
  }
  if (t < HH) sb[t] = bias[t];
  if (t < BNODES) {
    lhist[t] = 0;
    sBatch[t] = batch[nbase + t];
  }
  {
    const unsigned* rs = (const unsigned*)(hin + (size_t)nbase * DIN);
    unsigned* rd = (unsigned*)roots;
    for (int i = t; i < BNODES * DIN / 2; i += 512) rd[i] = rs[i];
  }
  __syncthreads();

  int ecnt = cursor[b];
  if (ecnt > CAP) ecnt = CAP;
  const unsigned int* mypay = pay + (size_t)b * CAP;

  unsigned ps[STASH];
#pragma unroll
  for (int u = 0; u < STASH; u++) {
    int i = t + u * 512;
    if (i < ecnt) {
      unsigned p = mypay[i];
      ps[u] = p;
      atomicAdd(&lhist[p >> SRC_BITS], 1);
    }
  }
  __syncthreads();

  int own = (t < BNODES) ? lhist[t] : 0;
  if (t < 256) ss[t] = own;
  __syncthreads();
  for (int off = 1; off < 256; off <<= 1) {
    int a0 = (t < 256 && t >= off) ? ss[t - off] : 0;
    __syncthreads();
    if (t < 256) ss[t] += a0;
    __syncthreads();
  }
  if (t < BNODES) {
    int ex = ss[t] - own;
    sRofs[t] = ex;
    sRend[t] = ex + own;
    lcur[t] = 0;
  }
  __syncthreads();

#pragma unroll
  for (int u = 0; u < STASH; u++) {
    int i = t + u * 512;
    if (i < ecnt) {
      unsigned p = ps[u];
      int ld = p >> SRC_BITS;
      int r = atomicAdd(&lcur[ld], 1);
      sSrc[sRofs[ld] + r] = (int)(p & SRC_MASK);
    }
  }
  __syncthreads();

  for (int task = t; task < BNODES * 5; task += 512) {
    int ln = task / 5;
    int c = task - ln * 5;
    int k0 = sRofs[ln], k1 = sRend[ln];
    float a0 = 0, a1 = 0, a2 = 0, a3 = 0;
    const unsigned short* xb = hin + c * 4;
    for (int k = k0; k < k1; k++) {
      int s = sSrc[k];
      uint2 u = *(const uint2*)(xb + (size_t)s * 20);
      a0 += bflo(u.x);
      a1 += bfhi(u.x);
      a2 += bflo(u.y);
      a3 += bfhi(u.y);
    }
    float* a = acc + ln * AST + c * 4;
    a[0] = a0; a[1] = a1; a[2] = a2; a[3] = a3;
  }
  __syncthreads();

  // dense into registers (acc is still being read), then overwrite acc
  float vreg[8];
#pragma unroll
  for (int u = 0; u < 8; u++) {
    int idx = t + u * 512;
    if (idx < BNODES * HH) {
      int ln = idx / HH;
      int j = idx - ln * HH;
      const float* a = acc + ln * AST;
      const unsigned short* r = roots + ln * DIN;
      float v = sb[j];
#pragma unroll
      for (int f = 0; f < DIN; f++) {
        v += a[f] * sWrel[f * HH + j];
        v += bflo((unsigned)r[f]) * sWroot[f * HH + j];
      }
      vreg[u] = fmaxf(v, 0.0f);
    }
  }
  __syncthreads();
#pragma unroll
  for (int u = 0; u < 8; u++) {
    int idx = t + u * 512;
    if (idx < BNODES * HH) {
      int ln = idx / HH;
      int j = idx - ln * HH;
      acc[ln * AST + j] = vreg[u];
    }
  }
  __syncthreads();

  // block-local pool over the graphs this bucket spans
  int g0 = sBatch[0];
  int g1 = sBatch[BNODES - 1];
  int ngr = g1 - g0 + 1;
  for (int it = t; it < ngr * HH; it += 512) {
    int gi = it / HH;
    int j = it - gi * HH;
    int g = g0 + gi;
    float s = 0.0f, m = 0.0f;
    int c = 0;
    for (int ln = 0; ln < BNODES; ln++) {
      if (sBatch[ln] == g) {
        float v = acc[ln * AST + j];
        s += v;
        m = fmaxf(m, v);
        c++;
      }
    }
    if (c) {
      atomicAdd(&sump[g * HH + j], s);
      atomicMax(&maxp[g * HH + j], __float_as_int(m));
      if (j == 0) atomicAdd(&cnt[g], (float)c);
    }
  }
}

__global__ __launch_bounds__(256) void readout_kernel(
    const float* __restrict__ sump, const int* __restrict__ maxp,
    const float* __restrict__ cnt, const float* __restrict__ Wlin,
    const float* __restrict__ blin, float* __restrict__ out) {
  int idx = blockIdx.x * 256 + threadIdx.x;
  if (idx >= GG * LL) return;
  int g = idx / LL;
  int l = idx - g * LL;
  float c = cnt[g];
  float inv = 1.0f / fmaxf(c, 1.0f);
  float acc = blin[l];
#pragma unroll
  for (int j = 0; j < HH; j++) {
    float mx = __int_as_float(maxp[g * HH + j]);
    float mean = sump[g * HH + j] * inv;
    acc += mx * Wlin[j * LL + l];
    acc += mean * Wlin[(HH + j) * LL + l];
  }
  out[idx] = acc;
}

extern "C" void kernel_launch(void* const* d_in, const int* in_sizes, int n_in,
                              void* d_out, int out_size, void* d_ws,
                              size_t ws_size, hipStream_t stream) {
  const float* x = (const float*)d_in[0];
  const int* edge_index = (const int*)d_in[1];
  const int* batch = (const int*)d_in[2];
  const float* W_rel1 = (const float*)d_in[3];
  const float* b1 = (const float*)d_in[4];
  const float* W_root1 = (const float*)d_in[5];
  const float* W_rel2 = (const float*)d_in[6];
  const float* b2 = (const float*)d_in[7];
  const float* W_root2 = (const float*)d_in[8];
  const float* W_rel3 = (const float*)d_in[9];
  const float* b3 = (const float*)d_in[10];
  const float* W_root3 = (const float*)d_in[11];
  const float* W_lin = (const float*)d_in[12];
  const float* b_lin = (const float*)d_in[13];
  float* out = (float*)d_out;

  const int E = in_sizes[1] / 2;
  const int n_nodes = in_sizes[0] / FF;  // == NN
  const int* src = edge_index;
  const int* dst = edge_index + E;

  // Workspace layout (chunks 16B aligned)
  unsigned int* pay = (unsigned int*)d_ws;       // NB*CAP u32 (14.3MB)
  int* cursor = (int*)(pay + (size_t)NB * CAP);  // 512
  float* sump = (float*)(cursor + 512);          // GG*HH
  int* maxp = (int*)(sump + GG * HH);            // GG*HH
  float* cnt = (float*)(maxp + GG * HH);         // 512
  unsigned short* xb = (unsigned short*)(cnt + 512);  // NN*FF bf16 (2MB)
  unsigned short* h1 = xb + (size_t)NN * FF;     // NN*HH bf16 (4MB)
  unsigned short* h2 = h1 + (size_t)NN * HH;     // NN*HH bf16 (4MB)

  const int edge_tiles = (E + TILE - 1) / TILE;

  // ---- Cast x to bf16 + zero accumulators/cursors ----
  cast_init_kernel<<<(n_nodes * FF + 255) / 256, 256, 0, stream>>>(
      x, xb, sump, maxp, cnt, cursor, n_nodes * FF);

  // ---- Edge partition: staged multisplit into fixed bucket regions ----
  multisplit_kernel<<<edge_tiles, 256, 0, stream>>>(src, dst, cursor, pay, E);

  // ---- Fused per-bucket layers (register-accumulated) ----
  bucket_layer_kernel<FF><<<NB, 512, 0, stream>>>(
      pay, cursor, xb, W_rel1, b1, W_root1, h1);
  bucket_layer_kernel<HH><<<NB, 512, 0, stream>>>(
      pay, cursor, h1, W_rel2, b2, W_root2, h2);
  bucket_layer_pool_kernel<<<NB, 512, 0, stream>>>(
      pay, cursor, h2, W_rel3, b3, W_root3, batch, sump, maxp, cnt);

  // ---- Readout ----
  readout_kernel<<<(GG * LL + 255) / 256, 256, 0, stream>>>(
      sump, maxp, cnt, W_lin, b_lin, out);
}